// Round 2
// baseline (444.578 us; speedup 1.0000x reference)
//
#include <hip/hip_runtime.h>
#include <hip/hip_bf16.h>

// B=2, C=8, L=1024, H=512
// out[((b*1024+l)*1024+m)*8 + c] = a[b,c,l] + bb[b,c,m] + sum_h start*v4*end
//
// Single fused kernel. WG tile = 64(l) x 64(m) x all 8 c-planes, K=512 in 16
// steps of BK=32. Wave w computes the full 64x64 for planes {2w, 2w+1}.
// a (start.(v1+v3)) and bb (end.(v2-v3)) are accumulated during staging and
// reduced at the end (no prepass kernel). One WG owns all 8 c of every output
// line -> full 128B lines assemble in one XCD's L2 (kills write amplification).

typedef short bf16x8 __attribute__((ext_vector_type(8)));
typedef float f32x4 __attribute__((ext_vector_type(4)));

__device__ __forceinline__ unsigned pk2(float x, float y) {
    union { __hip_bfloat162 h; unsigned u; } cv;
    cv.h = __float22bfloat162_rn(make_float2(x, y));
    return cv.u;
}

// LDS layout with row-pair XOR swizzle (no padding; 2-way bank access = free).
// logical (plane, row 0..63, chunk j 0..3 of 8 bf16) -> ushort offset
__device__ __forceinline__ int lds_off(int plane, int row, int j) {
    const int rp = row >> 1;
    const int pc = (j + ((row & 1) << 2)) ^ (rp & 7);
    return plane * 2048 + rp * 64 + pc * 8;
}

__global__ __launch_bounds__(256, 2) void fused_k(const float* __restrict__ sh,
                                                  const float* __restrict__ eh,
                                                  const float* __restrict__ v,
                                                  float* __restrict__ out) {
    __shared__ __align__(16) unsigned short As[8 * 2048];   // 32 KB
    __shared__ __align__(16) unsigned short Bs[8 * 2048];   // 32 KB

    const int t   = threadIdx.x;
    const int bid = blockIdx.x;
    // XCD swizzle: all 16 mt-blocks of a (b,lt) strip land on one XCD.
    const int xcd  = bid & 7, slot = bid >> 3;
    const int b    = xcd >> 2;
    const int lt   = (xcd & 3) * 4 + (slot >> 4);
    const int mt   = slot & 15;

    const int lane = t & 63, wave = t >> 6;
    const int ln15 = lane & 15, quad = lane >> 4;

    const int rowt = t >> 2;   // staging row 0..63
    const int jt   = t & 3;    // staging k-chunk

    const float* baseA = sh + (size_t)b * 8 * 524288 + ((size_t)lt * 64 + rowt) * 512;
    const float* baseB = eh + (size_t)b * 8 * 524288 + ((size_t)mt * 64 + rowt) * 512;

    f32x4 acc[2][4][4] = {};
    float sa[8] = {0,0,0,0,0,0,0,0};
    float sb[8] = {0,0,0,0,0,0,0,0};

    for (int ks = 0; ks < 16; ++ks) {
        const int k0 = ks * 32 + jt * 8;

        // weight slices for this thread's fixed k-chunk (v is 8KB -> L1)
        float4 w1a = *(const float4*)(v + k0);          float4 w1b = *(const float4*)(v + k0 + 4);
        float4 w2a = *(const float4*)(v + 512 + k0);    float4 w2b = *(const float4*)(v + 512 + k0 + 4);
        float4 w3a = *(const float4*)(v + 1024 + k0);   float4 w3b = *(const float4*)(v + 1024 + k0 + 4);
        float4 w4a = *(const float4*)(v + 1536 + k0);   float4 w4b = *(const float4*)(v + 1536 + k0 + 4);
        const float4 wAa = make_float4(w1a.x + w3a.x, w1a.y + w3a.y, w1a.z + w3a.z, w1a.w + w3a.w);
        const float4 wAb = make_float4(w1b.x + w3b.x, w1b.y + w3b.y, w1b.z + w3b.z, w1b.w + w3b.w);
        const float4 wBa = make_float4(w2a.x - w3a.x, w2a.y - w3a.y, w2a.z - w3a.z, w2a.w - w3a.w);
        const float4 wBb = make_float4(w2b.x - w3b.x, w2b.y - w3b.y, w2b.z - w3b.z, w2b.w - w3b.w);

        // global loads (coalesced: a wave covers 16 rows x full 128B k-slice)
        float4 av[8][2], bv[8][2];
        #pragma unroll
        for (int p = 0; p < 8; ++p) {
            const float* pa = baseA + (size_t)p * 524288 + k0;
            const float* pb = baseB + (size_t)p * 524288 + k0;
            av[p][0] = *(const float4*)pa;  av[p][1] = *(const float4*)(pa + 4);
            bv[p][0] = *(const float4*)pb;  bv[p][1] = *(const float4*)(pb + 4);
        }

        __syncthreads();   // previous iteration's fragment reads complete

        #pragma unroll
        for (int p = 0; p < 8; ++p) {
            float4 a0 = av[p][0], a1 = av[p][1];
            float4 b0 = bv[p][0], b1 = bv[p][1];
            sa[p] += a0.x*wAa.x + a0.y*wAa.y + a0.z*wAa.z + a0.w*wAa.w
                   + a1.x*wAb.x + a1.y*wAb.y + a1.z*wAb.z + a1.w*wAb.w;
            sb[p] += b0.x*wBa.x + b0.y*wBa.y + b0.z*wBa.z + b0.w*wBa.w
                   + b1.x*wBb.x + b1.y*wBb.y + b1.z*wBb.z + b1.w*wBb.w;
            a0.x *= w4a.x; a0.y *= w4a.y; a0.z *= w4a.z; a0.w *= w4a.w;
            a1.x *= w4b.x; a1.y *= w4b.y; a1.z *= w4b.z; a1.w *= w4b.w;
            uint4 pa, pb2;
            pa.x  = pk2(a0.x, a0.y); pa.y  = pk2(a0.z, a0.w);
            pa.z  = pk2(a1.x, a1.y); pa.w  = pk2(a1.z, a1.w);
            pb2.x = pk2(b0.x, b0.y); pb2.y = pk2(b0.z, b0.w);
            pb2.z = pk2(b1.x, b1.y); pb2.w = pk2(b1.z, b1.w);
            *(uint4*)&As[lds_off(p, rowt, jt)] = pa;
            *(uint4*)&Bs[lds_off(p, rowt, jt)] = pb2;
        }

        __syncthreads();

        bf16x8 aF[2][4], bF[2][4];
        #pragma unroll
        for (int c2 = 0; c2 < 2; ++c2) {
            const int c = wave * 2 + c2;
            #pragma unroll
            for (int i = 0; i < 4; ++i) {
                aF[c2][i] = *(const bf16x8*)&As[lds_off(c, i * 16 + ln15, quad)];
                bF[c2][i] = *(const bf16x8*)&Bs[lds_off(c, i * 16 + ln15, quad)];
            }
        }
        #pragma unroll
        for (int c2 = 0; c2 < 2; ++c2)
            #pragma unroll
            for (int i = 0; i < 4; ++i)
                #pragma unroll
                for (int j = 0; j < 4; ++j)
                    acc[c2][i][j] = __builtin_amdgcn_mfma_f32_16x16x32_bf16(
                        aF[c2][i], bF[c2][j], acc[c2][i][j], 0, 0, 0);
    }

    // reduce a/bb partials across the 4 k-chunk threads (consecutive lanes)
    #pragma unroll
    for (int p = 0; p < 8; ++p) {
        sa[p] += __shfl_xor(sa[p], 1, 64); sa[p] += __shfl_xor(sa[p], 2, 64);
        sb[p] += __shfl_xor(sb[p], 1, 64); sb[p] += __shfl_xor(sb[p], 2, 64);
    }
    __syncthreads();                     // all fragment reads done; reuse As
    float* aS = (float*)As;              // a[plane][row]  : 512 floats
    float* bS = aS + 512;                // bb[plane][row] : 512 floats
    if (jt == 0) {
        #pragma unroll
        for (int p = 0; p < 8; ++p) {
            aS[p * 64 + rowt] = sa[p];
            bS[p * 64 + rowt] = sb[p];
        }
    }
    __syncthreads();

    // epilogue: float2 (c-pair) stores; all 8 c of a line come from this WG
    const int c0 = wave * 2;
    #pragma unroll
    for (int i = 0; i < 4; ++i)
        #pragma unroll
        for (int r = 0; r < 4; ++r) {
            const int ll = i * 16 + quad * 4 + r;
            const float a0 = aS[c0 * 64 + ll];
            const float a1 = aS[(c0 + 1) * 64 + ll];
            const size_t rowbase = (size_t)(b * 1024 + lt * 64 + ll) * 1024;
            #pragma unroll
            for (int j = 0; j < 4; ++j) {
                const int mm = j * 16 + ln15;
                float2 o;
                o.x = acc[0][i][j][r] + a0 + bS[c0 * 64 + mm];
                o.y = acc[1][i][j][r] + a1 + bS[(c0 + 1) * 64 + mm];
                *(float2*)&out[(rowbase + mt * 64 + mm) * 8 + c0] = o;
            }
        }
}

extern "C" void kernel_launch(void* const* d_in, const int* in_sizes, int n_in,
                              void* d_out, int out_size, void* d_ws, size_t ws_size,
                              hipStream_t stream) {
    const float* sh = (const float*)d_in[0];
    const float* eh = (const float*)d_in[1];
    const float* v  = (const float*)d_in[2];
    float* out = (float*)d_out;
    (void)d_ws; (void)ws_size;

    fused_k<<<512, 256, 0, stream>>>(sh, eh, v, out);
}